// Round 3
// baseline (363.437 us; speedup 1.0000x reference)
//
#include <hip/hip_runtime.h>

// Problem dims (fixed by the reference):
//   B=8192, P=2, L1=L2=9, N=25, F=128
//   x1: [B,2,9,128] f32, x2: [B,2,9,128] f32, cg: [9,9,25] f32
//   out: [B,1,2,25,128] f32
//
// out[b,0,0,n,f] = sum_{l,m} cg[l,m,n]*(x1e[l]*x2o[m] + x1o[l]*x2e[m])
// out[b,0,1,n,f] = sum_{l,m} cg[l,m,n]*(x1e[l]*x2o[m] + x1o[l]*x2o[m])
// (reference's eoo==eee bug reproduced: both channels share the x1e*x2o term)
//
// Round-3 structure:
//  - f-block=2: each thread owns 2 consecutive f's (float2 loads/stores).
//    The f-axis maps onto v_pk_fma_f32 lanes; per-wave cg-read count halves.
//  - cg staged in LDS once per block (rows padded 25->28 floats so every
//    4-float quad is 16B-aligned), read as uniform-address ds_read_b128
//    (broadcast: conflict-free). 567 ds ops/thread vs 2025 VMEM ops before.

#define B_DIM 8192
#define F_DIM 128
#define L_DIM 9
#define N_DIM 25
#define NPAD 28   // padded row: 112B, 16B-aligned quads

typedef __attribute__((ext_vector_type(2))) float v2f;

__device__ __forceinline__ v2f ntload2(const float* p) {
    v2f v;
    v.x = __builtin_nontemporal_load(p);
    v.y = __builtin_nontemporal_load(p + 1);
    return v;
}

__global__ __launch_bounds__(256) void tp_kernel(
    const float* __restrict__ x1,
    const float* __restrict__ x2,
    const float* __restrict__ cg,
    float* __restrict__ out)
{
    __shared__ float cgs[L_DIM * L_DIM * NPAD];  // 9072 B

    // cooperative cg stage: 2025 elements, rows repacked 25 -> 28 stride
    for (int i = threadIdx.x; i < L_DIM * L_DIM * N_DIM; i += 256) {
        const int r = i / N_DIM;
        const int c = i - r * N_DIM;
        cgs[r * NPAD + c] = cg[i];
    }
    __syncthreads();

    const int g = blockIdx.x * 256 + threadIdx.x;
    const int b = g >> 6;              // 64 f-pairs per b
    const int f = (g & 63) << 1;       // starting f of this thread's pair

    const float* x1b = x1 + (size_t)b * 2 * L_DIM * F_DIM + f;
    const float* x2b = x2 + (size_t)b * 2 * L_DIM * F_DIM + f;

    // x2 parity slices for both f's; m-loop fully unrolled -> static indices
    v2f x2e2[L_DIM], x2o2[L_DIM];
#pragma unroll
    for (int m = 0; m < L_DIM; ++m) {
        x2e2[m] = ntload2(x2b + m * F_DIM);             // p=0 (even)
        x2o2[m] = ntload2(x2b + (L_DIM + m) * F_DIM);   // p=1 (odd)
    }

    v2f acc0[N_DIM], acc1[N_DIM];
#pragma unroll
    for (int n = 0; n < N_DIM; ++n) { acc0[n] = (v2f)(0.0f); acc1[n] = (v2f)(0.0f); }

    // Outer l loop NOT unrolled (body ~550 insts; I$-friendly).
#pragma unroll 1
    for (int l = 0; l < L_DIM; ++l) {
        const v2f x1e2 = ntload2(x1b + l * F_DIM);
        const v2f x1o2 = ntload2(x1b + (L_DIM + l) * F_DIM);
        const float* cl = &cgs[l * (L_DIM * NPAD)];
#pragma unroll
        for (int m = 0; m < L_DIM; ++m) {
            // t shared between channels (reference's eoo==eee bug)
            const v2f t  = x1e2 * x2o2[m];
            const v2f s0 = __builtin_elementwise_fma(x1o2, x2e2[m], t); // ch0
            const v2f s1 = __builtin_elementwise_fma(x1o2, x2o2[m], t); // ch1
            const float* cm = cl + m * NPAD;
            // 6 uniform-address b128 quads (n=0..23) + scalar tail (n=24)
#pragma unroll
            for (int q = 0; q < 6; ++q) {
                const float4 c4 = *reinterpret_cast<const float4*>(cm + q * 4);
                acc0[q*4+0] = __builtin_elementwise_fma((v2f)(c4.x), s0, acc0[q*4+0]);
                acc1[q*4+0] = __builtin_elementwise_fma((v2f)(c4.x), s1, acc1[q*4+0]);
                acc0[q*4+1] = __builtin_elementwise_fma((v2f)(c4.y), s0, acc0[q*4+1]);
                acc1[q*4+1] = __builtin_elementwise_fma((v2f)(c4.y), s1, acc1[q*4+1]);
                acc0[q*4+2] = __builtin_elementwise_fma((v2f)(c4.z), s0, acc0[q*4+2]);
                acc1[q*4+2] = __builtin_elementwise_fma((v2f)(c4.z), s1, acc1[q*4+2]);
                acc0[q*4+3] = __builtin_elementwise_fma((v2f)(c4.w), s0, acc0[q*4+3]);
                acc1[q*4+3] = __builtin_elementwise_fma((v2f)(c4.w), s1, acc1[q*4+3]);
            }
            const float c24 = cm[24];
            acc0[24] = __builtin_elementwise_fma((v2f)(c24), s0, acc0[24]);
            acc1[24] = __builtin_elementwise_fma((v2f)(c24), s1, acc1[24]);
        }
    }

    // out[b,0,ch,n,f] -> ((b*2 + ch)*25 + n)*128 + f
    float* ob = out + (size_t)b * 2 * N_DIM * F_DIM + f;
#pragma unroll
    for (int n = 0; n < N_DIM; ++n) {
        __builtin_nontemporal_store(acc0[n].x, ob + n * F_DIM);
        __builtin_nontemporal_store(acc0[n].y, ob + n * F_DIM + 1);
        __builtin_nontemporal_store(acc1[n].x, ob + (N_DIM + n) * F_DIM);
        __builtin_nontemporal_store(acc1[n].y, ob + (N_DIM + n) * F_DIM + 1);
    }
}

extern "C" void kernel_launch(void* const* d_in, const int* in_sizes, int n_in,
                              void* d_out, int out_size, void* d_ws, size_t ws_size,
                              hipStream_t stream) {
    (void)in_sizes; (void)n_in; (void)out_size; (void)d_ws; (void)ws_size;
    const float* x1 = (const float*)d_in[0];
    const float* x2 = (const float*)d_in[1];
    const float* cg = (const float*)d_in[2];
    float* out = (float*)d_out;

    // B * F/2 threads, one (b, f-pair) each: 8192*64/256 = 2048 blocks
    const int threads = 256;
    const int blocks  = (B_DIM * (F_DIM / 2)) / threads;
    tp_kernel<<<blocks, threads, 0, stream>>>(x1, x2, cg, out);
}

// Round 4
// 338.748 us; speedup vs baseline: 1.0729x; 1.0729x over previous
//
#include <hip/hip_runtime.h>

// Problem dims (fixed by the reference):
//   B=8192, P=2, L1=L2=9, N=25, F=128
//   x1: [B,2,9,128] f32, x2: [B,2,9,128] f32, cg: [9,9,25] f32
//   out: [B,1,2,25,128] f32
//
// out[b,0,0,n,f] = sum_{l,m} cg[l,m,n]*(x1e[l]*x2o[m] + x1o[l]*x2e[m])
// out[b,0,1,n,f] = sum_{l,m} cg[l,m,n]*(x1e[l]*x2o[m] + x1o[l]*x2o[m])
// (reference's eoo==eee bug reproduced: both channels share the x1e*x2o term)
//
// Round-4 structure (post-mortem of LDS regression: 567 ds_read/wave x 32
// waves/CU ~ 84us of serialized LDS-pipe time -> LDS-bound):
//  - cg lives on the SMEM/scalar path: wave-uniform addresses into a
//    __device__ repacked copy -> compiler emits s_load_dwordx*; separate
//    pipe, scalar cache, zero LDS traffic.
//  - n-axis packed into v_pk_fma_f32: coefficient PAIR {cg[n],cg[n+1]} is
//    the (single allowed) SGPR operand read directly from consecutive
//    memory; s0/s1 splat once per (l,m), amortized over 26 pk_fmas.
//  - prep kernel repacks rows 25 -> stride 26 (+0 pad): keeps every pair
//    8B-aligned for all 81 rows and folds the n=24 tail into a full
//    pk_fma (pad lane accumulates 0*s -> never stored).

#define B_DIM 8192
#define F_DIM 128
#define L_DIM 9
#define N_DIM 25
#define NROW 26                  // padded row stride (even -> aligned pairs)
#define NPAIR 13                 // 13 pairs of n per row (incl. pad)

typedef __attribute__((ext_vector_type(2))) float v2f;

__device__ __align__(16) float g_cgp[L_DIM * L_DIM * NROW];  // 8424 B

__global__ __launch_bounds__(256) void cg_prep(const float* __restrict__ cg) {
    // repack [81][25] -> [81][26] with zero pad in col 25
    for (int i = threadIdx.x; i < L_DIM * L_DIM * NROW; i += 256) {
        const int row = i / NROW;
        const int c   = i - row * NROW;
        g_cgp[i] = (c < N_DIM) ? cg[row * N_DIM + c] : 0.0f;
    }
}

__global__ __launch_bounds__(256) void tp_kernel(
    const float* __restrict__ x1,
    const float* __restrict__ x2,
    float* __restrict__ out)
{
    const int g = blockIdx.x * 256 + threadIdx.x;
    const int b = g >> 7;      // g / F_DIM
    const int f = g & 127;     // g % F_DIM

    const float* x1b = x1 + (size_t)b * 2 * L_DIM * F_DIM + f;
    const float* x2b = x2 + (size_t)b * 2 * L_DIM * F_DIM + f;

    // x2 parity slices; m-loop fully unrolled -> static register indices
    float x2e[L_DIM], x2o[L_DIM];
#pragma unroll
    for (int m = 0; m < L_DIM; ++m) {
        x2e[m] = x2b[m * F_DIM];               // p=0 (even)
        x2o[m] = x2b[(L_DIM + m) * F_DIM];     // p=1 (odd)
    }

    // n-pair accumulators: acc[q] = {out[2q], out[2q+1]}; q=12.y is the pad
    v2f acc0[NPAIR], acc1[NPAIR];
#pragma unroll
    for (int q = 0; q < NPAIR; ++q) { acc0[q] = (v2f)(0.0f); acc1[q] = (v2f)(0.0f); }

    const float* __restrict__ cgp = g_cgp;

    // Outer l loop NOT unrolled: body ~300 insts, I$-friendly. All cgp
    // addresses are wave-uniform -> SMEM (s_load) path.
#pragma unroll 1
    for (int l = 0; l < L_DIM; ++l) {
        const float x1e = x1b[l * F_DIM];
        const float x1o = x1b[(L_DIM + l) * F_DIM];
        const float* cl = cgp + l * (L_DIM * NROW);
#pragma unroll
        for (int m = 0; m < L_DIM; ++m) {
            // t shared between channels (reference's eoo==eee bug)
            const float t  = x1e * x2o[m];
            const float s0 = fmaf(x1o, x2e[m], t);   // ch0: eee+ooe
            const float s1 = fmaf(x1o, x2o[m], t);   // ch1: eoo+oeo
            v2f s0v; s0v.x = s0; s0v.y = s0;         // splat once, reuse x13
            v2f s1v; s1v.x = s1; s1v.y = s1;
            const float* cm = cl + m * NROW;
#pragma unroll
            for (int q = 0; q < NPAIR; ++q) {
                v2f c2;                              // {cg[2q], cg[2q+1]} (uniform)
                c2.x = cm[q * 2];
                c2.y = cm[q * 2 + 1];
                acc0[q] = __builtin_elementwise_fma(c2, s0v, acc0[q]);
                acc1[q] = __builtin_elementwise_fma(c2, s1v, acc1[q]);
            }
        }
    }

    // out[b,0,ch,n,f] -> ((b*2 + ch)*25 + n)*128 + f
    float* ob = out + (size_t)b * 2 * N_DIM * F_DIM + f;
#pragma unroll
    for (int q = 0; q < NPAIR; ++q) {
        __builtin_nontemporal_store(acc0[q].x, ob + (2 * q) * F_DIM);
        __builtin_nontemporal_store(acc1[q].x, ob + (N_DIM + 2 * q) * F_DIM);
        if (q < NPAIR - 1) {  // q=12.y is the pad lane -> not stored
            __builtin_nontemporal_store(acc0[q].y, ob + (2 * q + 1) * F_DIM);
            __builtin_nontemporal_store(acc1[q].y, ob + (N_DIM + 2 * q + 1) * F_DIM);
        }
    }
}

extern "C" void kernel_launch(void* const* d_in, const int* in_sizes, int n_in,
                              void* d_out, int out_size, void* d_ws, size_t ws_size,
                              hipStream_t stream) {
    (void)in_sizes; (void)n_in; (void)out_size; (void)d_ws; (void)ws_size;
    const float* x1 = (const float*)d_in[0];
    const float* x2 = (const float*)d_in[1];
    const float* cg = (const float*)d_in[2];
    float* out = (float*)d_out;

    // 1) repack cg into padded __device__ array (stream-ordered before main)
    cg_prep<<<1, 256, 0, stream>>>(cg);

    // 2) main: B*F threads, one (b,f) each: 8192*128/256 = 4096 blocks
    const int threads = 256;
    const int blocks  = (B_DIM * F_DIM) / threads;
    tp_kernel<<<blocks, threads, 0, stream>>>(x1, x2, out);
}